// Round 11
// baseline (33.855 us; speedup 1.0000x reference)
//
#include <hip/hip_runtime.h>
#include <stdint.h>

#define D_ 128
#define HW_ 65536
#define GPB (HW_/4)            // 16384 float4 groups per depth-slice per (b,c)
#define K_ 4
#define NBC 4
#define NBLK 1024
#define SCALE_ 100000.0f
#define EPS_ 1e-15f

typedef unsigned int u32;

__device__ __forceinline__ u32 umax32(u32 a, u32 b) { return a > b ? a : b; }
__device__ __forceinline__ u32 umin32(u32 a, u32 b) { return a < b ? a : b; }
__device__ __forceinline__ void cswap(u32& hi, u32& lo) {
    u32 a = hi, b = lo; bool s = b > a; hi = s ? b : a; lo = s ? a : b;
}
// merge two desc-sorted 4-lists, keep top-4 (bitonic)
__device__ __forceinline__ void merge4(u32 a[4], const u32* b) {
    u32 m0 = umax32(a[0], b[3]);
    u32 m1 = umax32(a[1], b[2]);
    u32 m2 = umax32(a[2], b[1]);
    u32 m3 = umax32(a[3], b[0]);
    cswap(m0, m2); cswap(m1, m3); cswap(m0, m1); cswap(m2, m3);
    a[0] = m0; a[1] = m1; a[2] = m2; a[3] = m3;
}

// Keys: (relu_value_bits & ~0x7F) | (127 - d).  Values >= 0 -> bit-monotone;
// on truncated-value ties the larger low word = smaller d = lax.top_k order.
// Load shape: burst of 4 float4 per batch (R7/R10-proven); unroll 4 to let
// the scheduler keep ~2-3 batches of loads in flight. NO hand pipeline
// (R9: arrays demoted to scratch), NO 8-wide burst array (R8 regression).
__global__ __launch_bounds__(256, 4)
void topk_kernel(const float* __restrict__ x, float* __restrict__ out,
                 float2* __restrict__ ws) {
    const int b    = blockIdx.x;
    const int wv   = threadIdx.x >> 6;        // depth quarter 0..3
    const int lane = threadIdx.x & 63;
    const int bc   = b >> 8;                  // 256 blocks per (b,c)
    const int gg   = ((b & 255) << 6) | lane; // col-group within (b,c)

    const float4* __restrict__ src = (const float4*)x
        + (size_t)bc * (D_ * GPB) + (size_t)(wv * 32) * GPB + gg;

    u32 l[4][K_];                             // per-column top-4 keys, desc
    #pragma unroll
    for (int c = 0; c < 4; ++c)
        #pragma unroll
        for (int k = 0; k < K_; ++k) l[c][k] = 0u;  // phantom (v=0,d=127): harmless
    float mnraw = __int_as_float(0x7F800000); // +inf, min of RAW values

    const int dbase = wv * 32;
    #pragma unroll 4
    for (int batch = 0; batch < 8; ++batch) {
        float4 q[4];
        #pragma unroll
        for (int j = 0; j < 4; ++j)
            q[j] = src[(size_t)(batch * 4 + j) * GPB];
        #pragma unroll
        for (int j = 0; j < 4; ++j) {
            const int d = dbase + batch * 4 + j;
            const u32 low = (u32)(D_ - 1 - d);
            mnraw = fminf(mnraw, fminf(fminf(q[j].x, q[j].y),
                                       fminf(q[j].z, q[j].w)));
            const float vx[4] = { fmaxf(q[j].x, 0.0f), fmaxf(q[j].y, 0.0f),
                                  fmaxf(q[j].z, 0.0f), fmaxf(q[j].w, 0.0f) };
            #pragma unroll
            for (int c = 0; c < 4; ++c) {
                u32 t = (__float_as_uint(vx[c]) & 0xFFFFFF80u) | low;
                u32 o;
                o = umax32(l[c][0], t); t = umin32(l[c][0], t); l[c][0] = o;
                o = umax32(l[c][1], t); t = umin32(l[c][1], t); l[c][1] = o;
                o = umax32(l[c][2], t); t = umin32(l[c][2], t); l[c][2] = o;
                l[c][3] = umax32(l[c][3], t);
            }
        }
    }

    // ---- block min/max reduce -> ws[b] (plain store, no atomics) ----
    {
        float bmn = mnraw;
        u32 kmx = umax32(umax32(l[0][0], l[1][0]), umax32(l[2][0], l[3][0]));
        #pragma unroll
        for (int off = 32; off > 0; off >>= 1) {
            bmn = fminf(bmn, __shfl_xor(bmn, off));
            kmx = umax32(kmx, (u32)__shfl_xor((int)kmx, off));
        }
        __shared__ float smn[4];
        __shared__ u32 skx[4];
        if (lane == 0) { smn[wv] = bmn; skx[wv] = kmx; }
        __syncthreads();
        if (threadIdx.x == 0) {
            float m0 = fminf(fminf(smn[0], smn[1]), fminf(smn[2], smn[3]));
            u32  x0 = umax32(umax32(skx[0], skx[1]), umax32(skx[2], skx[3]));
            // min over relu'd = relu(min over raw); max from truncated key
            ws[b] = make_float2(fmaxf(m0, 0.0f),
                                __uint_as_float(x0 & 0xFFFFFF80u));
        }
    }

    // ---- merge the 4 depth-quarters via LDS (2 stages) ----
    __shared__ u32 sk[2][64][17];             // pad 16->17: no bank conflicts
    if (wv >= 2) {
        #pragma unroll
        for (int c = 0; c < 4; ++c)
            #pragma unroll
            for (int k = 0; k < K_; ++k)
                sk[wv - 2][lane][c * 4 + k] = l[c][k];
    }
    __syncthreads();
    if (wv < 2) {
        #pragma unroll
        for (int c = 0; c < 4; ++c)
            merge4(l[c], &sk[wv][lane][c * 4]);
    }
    __syncthreads();
    if (wv == 1) {
        #pragma unroll
        for (int c = 0; c < 4; ++c)
            #pragma unroll
            for (int k = 0; k < K_; ++k)
                sk[0][lane][c * 4 + k] = l[c][k];
    }
    __syncthreads();

    // ---- wave 0: write raw (truncated) pred values + final dep channel ----
    if (wv == 0) {
        #pragma unroll
        for (int c = 0; c < 4; ++c)
            merge4(l[c], &sk[0][lane][c * 4]);

        float4* out4 = (float4*)out;
        const size_t pb = (size_t)(bc * 2 * K_) * GPB + gg;   // pred channel
        const size_t db = pb + (size_t)K_ * GPB;              // dep channel
        #pragma unroll
        for (int k = 0; k < K_; ++k) {
            float4 pv, dv;
            pv.x = __uint_as_float(l[0][k] & 0xFFFFFF80u);
            pv.y = __uint_as_float(l[1][k] & 0xFFFFFF80u);
            pv.z = __uint_as_float(l[2][k] & 0xFFFFFF80u);
            pv.w = __uint_as_float(l[3][k] & 0xFFFFFF80u);
            dv.x = (float)(l[0][k] & 0x7Fu) * (1.0f / 127.0f);
            dv.y = (float)(l[1][k] & 0x7Fu) * (1.0f / 127.0f);
            dv.z = (float)(l[2][k] & 0x7Fu) * (1.0f / 127.0f);
            dv.w = (float)(l[3][k] & 0x7Fu) * (1.0f / 127.0f);
            out4[pb + (size_t)k * GPB] = pv;
            out4[db + (size_t)k * GPB] = dv;
        }
    }
}

// Block reduces its (b,c)'s 256 ws partials (L2-resident), then normalizes
// one float4 of the pred channel in place.
__global__ __launch_bounds__(256)
void norm_kernel(float* __restrict__ out, const float2* __restrict__ ws) {
    const int b  = blockIdx.x;
    const int t  = threadIdx.x;
    const int bc = b >> 8;                    // 256 blocks per (b,c)

    const float2 a = ws[(bc << 8) + t];       // exactly the 256 partials of bc
    float mn = a.x, mx = a.y;
    #pragma unroll
    for (int off = 32; off > 0; off >>= 1) {
        mn = fminf(mn, __shfl_xor(mn, off));
        mx = fmaxf(mx, __shfl_xor(mx, off));
    }
    __shared__ float smn[4], smx[4];
    const int wv = t >> 6;
    if ((t & 63) == 0) { smn[wv] = mn; smx[wv] = mx; }
    __syncthreads();
    mn = fminf(fminf(smn[0], smn[1]), fminf(smn[2], smn[3]));
    mx = fmaxf(fmaxf(smx[0], smx[1]), fmaxf(smx[2], smx[3]));
    const float scl = SCALE_ / ((mx - mn) + EPS_);

    const int i = ((b & 255) << 8) | t;       // 0..65535 within bc's pred ch
    float4* out4 = (float4*)out;
    const size_t idx = (size_t)(bc * 2 * K_) * GPB + i;
    float4 v = out4[idx];
    v.x = (v.x - mn) * scl;
    v.y = (v.y - mn) * scl;
    v.z = (v.z - mn) * scl;
    v.w = (v.w - mn) * scl;
    out4[idx] = v;
}

extern "C" void kernel_launch(void* const* d_in, const int* in_sizes, int n_in,
                              void* d_out, int out_size, void* d_ws, size_t ws_size,
                              hipStream_t stream) {
    const float* x = (const float*)d_in[0];
    float* out = (float*)d_out;
    float2* ws = (float2*)d_ws;

    hipLaunchKernelGGL(topk_kernel, dim3(NBLK), dim3(256), 0, stream, x, out, ws);
    hipLaunchKernelGGL(norm_kernel, dim3(NBLK), dim3(256), 0, stream, out, ws);
}

// Round 12
// 31.763 us; speedup vs baseline: 1.0658x; 1.0658x over previous
//
#include <hip/hip_runtime.h>
#include <stdint.h>

#define D_ 128
#define HW_ 65536
#define GPB (HW_/4)            // 16384 float4 groups per depth-slice per (b,c)
#define K_ 4
#define NBC 4
#define NBLK 1024
#define SCALE_ 100000.0f
#define EPS_ 1e-15f

typedef unsigned int u32;

__device__ __forceinline__ u32 umax32(u32 a, u32 b) { return a > b ? a : b; }
__device__ __forceinline__ u32 umin32(u32 a, u32 b) { return a < b ? a : b; }
__device__ __forceinline__ void cswap(u32& hi, u32& lo) {
    u32 a = hi, b = lo; bool s = b > a; hi = s ? b : a; lo = s ? a : b;
}
// merge two desc-sorted 4-lists, keep top-4 (bitonic)
__device__ __forceinline__ void merge4(u32 a[4], const u32* b) {
    u32 m0 = umax32(a[0], b[3]);
    u32 m1 = umax32(a[1], b[2]);
    u32 m2 = umax32(a[2], b[1]);
    u32 m3 = umax32(a[3], b[0]);
    cswap(m0, m2); cswap(m1, m3); cswap(m0, m1); cswap(m2, m3);
    a[0] = m0; a[1] = m1; a[2] = m2; a[3] = m3;
}

// Keys: (relu_value_bits & ~0x7F) | (127 - d).  Values >= 0 -> bit-monotone;
// on truncated-value ties the larger low word = smaller d = lax.top_k order.
// R10 configuration exactly: burst of 4 float4 per batch, unroll 2 (sweep
// optimum: unroll 4 regressed, burst 8 regressed, hand pipeline spilled).
__global__ __launch_bounds__(256, 4)
void topk_kernel(const float* __restrict__ x, float* __restrict__ out,
                 float2* __restrict__ ws) {
    const int b    = blockIdx.x;
    const int wv   = threadIdx.x >> 6;        // depth quarter 0..3
    const int lane = threadIdx.x & 63;
    const int bc   = b >> 8;                  // 256 blocks per (b,c)
    const int gg   = ((b & 255) << 6) | lane; // col-group within (b,c)

    const float4* __restrict__ src = (const float4*)x
        + (size_t)bc * (D_ * GPB) + (size_t)(wv * 32) * GPB + gg;

    u32 l[4][K_];                             // per-column top-4 keys, desc
    #pragma unroll
    for (int c = 0; c < 4; ++c)
        #pragma unroll
        for (int k = 0; k < K_; ++k) l[c][k] = 0u;  // phantom (v=0,d=127): harmless
    float mnraw = __int_as_float(0x7F800000); // +inf, min of RAW values

    const int dbase = wv * 32;
    #pragma unroll 2
    for (int batch = 0; batch < 8; ++batch) {
        float4 q[4];
        #pragma unroll
        for (int j = 0; j < 4; ++j)
            q[j] = src[(size_t)(batch * 4 + j) * GPB];
        #pragma unroll
        for (int j = 0; j < 4; ++j) {
            const int d = dbase + batch * 4 + j;
            const u32 low = (u32)(D_ - 1 - d);
            mnraw = fminf(mnraw, fminf(fminf(q[j].x, q[j].y),
                                       fminf(q[j].z, q[j].w)));
            const float vx[4] = { fmaxf(q[j].x, 0.0f), fmaxf(q[j].y, 0.0f),
                                  fmaxf(q[j].z, 0.0f), fmaxf(q[j].w, 0.0f) };
            #pragma unroll
            for (int c = 0; c < 4; ++c) {
                u32 t = (__float_as_uint(vx[c]) & 0xFFFFFF80u) | low;
                u32 o;
                o = umax32(l[c][0], t); t = umin32(l[c][0], t); l[c][0] = o;
                o = umax32(l[c][1], t); t = umin32(l[c][1], t); l[c][1] = o;
                o = umax32(l[c][2], t); t = umin32(l[c][2], t); l[c][2] = o;
                l[c][3] = umax32(l[c][3], t);
            }
        }
    }

    // ---- block min/max reduce -> ws[b] (plain store, no atomics) ----
    {
        float bmn = mnraw;
        u32 kmx = umax32(umax32(l[0][0], l[1][0]), umax32(l[2][0], l[3][0]));
        #pragma unroll
        for (int off = 32; off > 0; off >>= 1) {
            bmn = fminf(bmn, __shfl_xor(bmn, off));
            kmx = umax32(kmx, (u32)__shfl_xor((int)kmx, off));
        }
        __shared__ float smn[4];
        __shared__ u32 skx[4];
        if (lane == 0) { smn[wv] = bmn; skx[wv] = kmx; }
        __syncthreads();
        if (threadIdx.x == 0) {
            float m0 = fminf(fminf(smn[0], smn[1]), fminf(smn[2], smn[3]));
            u32  x0 = umax32(umax32(skx[0], skx[1]), umax32(skx[2], skx[3]));
            // min over relu'd = relu(min over raw); max from truncated key
            ws[b] = make_float2(fmaxf(m0, 0.0f),
                                __uint_as_float(x0 & 0xFFFFFF80u));
        }
    }

    // ---- merge the 4 depth-quarters via LDS (2 stages) ----
    __shared__ u32 sk[2][64][17];             // pad 16->17: no bank conflicts
    if (wv >= 2) {
        #pragma unroll
        for (int c = 0; c < 4; ++c)
            #pragma unroll
            for (int k = 0; k < K_; ++k)
                sk[wv - 2][lane][c * 4 + k] = l[c][k];
    }
    __syncthreads();
    if (wv < 2) {
        #pragma unroll
        for (int c = 0; c < 4; ++c)
            merge4(l[c], &sk[wv][lane][c * 4]);
    }
    __syncthreads();
    if (wv == 1) {
        #pragma unroll
        for (int c = 0; c < 4; ++c)
            #pragma unroll
            for (int k = 0; k < K_; ++k)
                sk[0][lane][c * 4 + k] = l[c][k];
    }
    __syncthreads();

    // ---- wave 0: write raw (truncated) pred values + final dep channel ----
    if (wv == 0) {
        #pragma unroll
        for (int c = 0; c < 4; ++c)
            merge4(l[c], &sk[0][lane][c * 4]);

        float4* out4 = (float4*)out;
        const size_t pb = (size_t)(bc * 2 * K_) * GPB + gg;   // pred channel
        const size_t db = pb + (size_t)K_ * GPB;              // dep channel
        #pragma unroll
        for (int k = 0; k < K_; ++k) {
            float4 pv, dv;
            pv.x = __uint_as_float(l[0][k] & 0xFFFFFF80u);
            pv.y = __uint_as_float(l[1][k] & 0xFFFFFF80u);
            pv.z = __uint_as_float(l[2][k] & 0xFFFFFF80u);
            pv.w = __uint_as_float(l[3][k] & 0xFFFFFF80u);
            dv.x = (float)(l[0][k] & 0x7Fu) * (1.0f / 127.0f);
            dv.y = (float)(l[1][k] & 0x7Fu) * (1.0f / 127.0f);
            dv.z = (float)(l[2][k] & 0x7Fu) * (1.0f / 127.0f);
            dv.w = (float)(l[3][k] & 0x7Fu) * (1.0f / 127.0f);
            out4[pb + (size_t)k * GPB] = pv;
            out4[db + (size_t)k * GPB] = dv;
        }
    }
}

// Block reduces its (b,c)'s 256 ws partials (L2-resident), then normalizes
// one float4 of the pred channel in place.
__global__ __launch_bounds__(256)
void norm_kernel(float* __restrict__ out, const float2* __restrict__ ws) {
    const int b  = blockIdx.x;
    const int t  = threadIdx.x;
    const int bc = b >> 8;                    // 256 blocks per (b,c)

    const float2 a = ws[(bc << 8) + t];       // exactly the 256 partials of bc
    float mn = a.x, mx = a.y;
    #pragma unroll
    for (int off = 32; off > 0; off >>= 1) {
        mn = fminf(mn, __shfl_xor(mn, off));
        mx = fmaxf(mx, __shfl_xor(mx, off));
    }
    __shared__ float smn[4], smx[4];
    const int wv = t >> 6;
    if ((t & 63) == 0) { smn[wv] = mn; smx[wv] = mx; }
    __syncthreads();
    mn = fminf(fminf(smn[0], smn[1]), fminf(smn[2], smn[3]));
    mx = fmaxf(fmaxf(smx[0], smx[1]), fmaxf(smx[2], smx[3]));
    const float scl = SCALE_ / ((mx - mn) + EPS_);

    const int i = ((b & 255) << 8) | t;       // 0..65535 within bc's pred ch
    float4* out4 = (float4*)out;
    const size_t idx = (size_t)(bc * 2 * K_) * GPB + i;
    float4 v = out4[idx];
    v.x = (v.x - mn) * scl;
    v.y = (v.y - mn) * scl;
    v.z = (v.z - mn) * scl;
    v.w = (v.w - mn) * scl;
    out4[idx] = v;
}

extern "C" void kernel_launch(void* const* d_in, const int* in_sizes, int n_in,
                              void* d_out, int out_size, void* d_ws, size_t ws_size,
                              hipStream_t stream) {
    const float* x = (const float*)d_in[0];
    float* out = (float*)d_out;
    float2* ws = (float2*)d_ws;

    hipLaunchKernelGGL(topk_kernel, dim3(NBLK), dim3(256), 0, stream, x, out, ws);
    hipLaunchKernelGGL(norm_kernel, dim3(NBLK), dim3(256), 0, stream, out, ws);
}